// Round 7
// baseline (270.942 us; speedup 1.0000x reference)
//
#include <hip/hip_runtime.h>
#include <hip/hip_bf16.h>

#define BSZ   2
#define LSEQ  4096
#define DH    512
#define NH    8
#define HDIM  64

typedef unsigned short ushort_t;
typedef __attribute__((ext_vector_type(8))) short s8v;    // 8 bf16 = 4 VGPRs
typedef __attribute__((ext_vector_type(4))) short s4v;    // 4 bf16 = 2 VGPRs
typedef __attribute__((ext_vector_type(4))) float f4v;    // MFMA accumulator

__device__ __forceinline__ ushort_t f2bf(float f) {
    __hip_bfloat16 h = __float2bfloat16(f);
    return *(ushort_t*)&h;
}

// async global->LDS, 16B per lane; LDS dest = wave-uniform base + lane*16B
__device__ __forceinline__ void gld_lds16(const ushort_t* g, ushort_t* l) {
    __builtin_amdgcn_global_load_lds(
        (const __attribute__((address_space(1))) void*)g,
        (__attribute__((address_space(3))) void*)l, 16, 0, 0);
}

// ---------------------------------------------------------------------------
__global__ __launch_bounds__(256) void cast_bf16(const float* __restrict__ src,
                                                 ushort_t* __restrict__ dst, int n)
{
    int i = (blockIdx.x * 256 + threadIdx.x) * 4;
    if (i + 3 < n) {
        float4 v = *(const float4*)&src[i];
        ushort_t o[4] = {f2bf(v.x), f2bf(v.y), f2bf(v.z), f2bf(v.w)};
        *(uint2*)&dst[i] = *(uint2*)o;
    }
}

// ---------------------------------------------------------------------------
__global__ __launch_bounds__(256) void transpose_cast(const float* __restrict__ src,
                                                      ushort_t* __restrict__ dst,
                                                      int R, int C)
{
    __shared__ float tile[32][33];
    int r0 = blockIdx.y * 32, c0 = blockIdx.x * 32;
    int t = threadIdx.x;
    int tr = t >> 5, tc = t & 31;
    #pragma unroll
    for (int i = 0; i < 4; i++)
        tile[tr + 8 * i][tc] = src[(size_t)(r0 + tr + 8 * i) * C + c0 + tc];
    __syncthreads();
    #pragma unroll
    for (int i = 0; i < 4; i++) {
        int oc = tr + 8 * i;
        dst[(size_t)(c0 + oc) * R + r0 + tc] = f2bf(tile[tc][oc]);
    }
}

// ---------------------------------------------------------------------------
__global__ __launch_bounds__(256) void vtrans(const ushort_t* __restrict__ qkv,
                                              ushort_t* __restrict__ vt)
{
    __shared__ ushort_t T[64][72];
    const int lt = blockIdx.x, h = blockIdx.y, b = blockIdx.z;
    const int l0 = lt * 64;
    const int t = threadIdx.x;
    {
        int r = t >> 2, c = (t & 3) * 16;
        size_t g = ((size_t)(b * LSEQ + l0 + r)) * (3 * DH) + 2 * DH + h * HDIM + c;
        *(uint4*)&T[r][c]     = *(const uint4*)&qkv[g];
        *(uint4*)&T[r][c + 8] = *(const uint4*)&qkv[g + 8];
    }
    __syncthreads();
    {
        int d = t >> 2, cl = (t & 3) * 16;
        ushort_t tmp[16];
        #pragma unroll
        for (int j = 0; j < 16; j++) tmp[j] = T[cl + j][d];
        size_t g = ((size_t)((b * NH + h) * 64 + d)) * LSEQ + l0 + cl;
        *(uint4*)&vt[g]     = *(uint4*)&tmp[0];
        *(uint4*)&vt[g + 8] = *(uint4*)&tmp[8];
    }
}

// ---------------------------------------------------------------------------
// bf16 MFMA GEMM (m97 structure), unchanged from R5.
// ---------------------------------------------------------------------------
template <typename OUT>
__global__ __launch_bounds__(256) void gemm_bt(const ushort_t* __restrict__ A,
                                               const ushort_t* __restrict__ Bt,
                                               const float* __restrict__ bias,
                                               OUT* __restrict__ C,
                                               int M, int N, int K)
{
    __shared__ ushort_t As[128 * 32];
    __shared__ ushort_t Bs[128 * 32];
    const int tid = threadIdx.x;
    const int row0 = blockIdx.y * 128, col0 = blockIdx.x * 128;
    const int wid = tid >> 6, lane = tid & 63;
    const int wm = wid >> 1, wn = wid & 1;
    const int quad = lane >> 4, ln = lane & 15;

    f4v acc[4][4] = {};

    const int srow = (lane >> 2);
    const int scol = (lane & 3) * 8;

    for (int k0 = 0; k0 < K; k0 += 32) {
        #pragma unroll
        for (int t = 0; t < 2; t++) {
            int chunk = wid * 2 + t;
            int r = chunk * 16 + srow;
            gld_lds16(&A[(size_t)(row0 + r) * K + k0 + scol], &As[chunk * 512]);
            gld_lds16(&Bt[(size_t)(col0 + r) * K + k0 + scol], &Bs[chunk * 512]);
        }
        __syncthreads();
        s8v af[4], bf[4];
        #pragma unroll
        for (int mt = 0; mt < 4; mt++)
            af[mt] = *(const s8v*)&As[(wm * 64 + mt * 16 + ln) * 32 + quad * 8];
        #pragma unroll
        for (int nt = 0; nt < 4; nt++)
            bf[nt] = *(const s8v*)&Bs[(wn * 64 + nt * 16 + ln) * 32 + quad * 8];
        #pragma unroll
        for (int mt = 0; mt < 4; mt++)
            #pragma unroll
            for (int nt = 0; nt < 4; nt++)
                acc[mt][nt] = __builtin_amdgcn_mfma_f32_16x16x32_bf16(
                    af[mt], bf[nt], acc[mt][nt], 0, 0, 0);
        __syncthreads();
    }

    #pragma unroll
    for (int mt = 0; mt < 4; mt++) {
        #pragma unroll
        for (int nt = 0; nt < 4; nt++) {
            int c = col0 + wn * 64 + nt * 16 + ln;
            float bv = bias[c];
            #pragma unroll
            for (int reg = 0; reg < 4; reg++) {
                int r = row0 + wm * 64 + mt * 16 + quad * 4 + reg;
                float v = acc[mt][nt][reg] + bv;
                if constexpr (sizeof(OUT) == 2)
                    C[(size_t)r * N + c] = (OUT)f2bf(v);
                else
                    C[(size_t)r * N + c] = v;
            }
        }
    }
}

// ---------------------------------------------------------------------------
// Flash v4: wave-split-k. Block = (b, h, q-tile pair {63-p, p}) -> uniform
// 65 iters/block, 512 blocks. Per kt: each wave owns a 16-k quarter:
//   S^T = K_q @ Q^T (16x16x32), C-layout == A-layout of K=16 MFMA
//   -> P stays in registers; PV via mfma_f32_16x16x16bf16_1k.
// Each wave accumulates O over all 64 q x 64 d for its k-quarter; merged
// once per tile via LDS atomicAdd, normalized by l (also atomically merged).
// ---------------------------------------------------------------------------
__global__ __launch_bounds__(256) void flash_mfma(const ushort_t* __restrict__ qkv,
                                                  const ushort_t* __restrict__ vt,
                                                  ushort_t* __restrict__ att)
{
    __shared__ ushort_t Ks[64 * 72];   // [kseq][d]
    __shared__ ushort_t Vs[64 * 72];   // [d][kseq]
    __shared__ float    Obuf[64 * 68]; // [q][d] fp32 merge buffer
    __shared__ float    lbuf[64];

    const int p = blockIdx.x;          // 0..31
    const int h = blockIdx.y, b = blockIdx.z;
    const int tid = threadIdx.x;
    const int w = tid >> 6, lane = tid & 63;
    const int quad = lane >> 4, ln = lane & 15;
    const int sr = tid >> 2, sc = (tid & 3) * 16;
    const int ldsw = sr * 72 + sc;
    const size_t kstep = (size_t)64 * 3 * DH;
    const float C_EXP = 0.18033688011112042f;  // 0.125 * log2(e)

    const int qts[2] = {63 - p, p};
    for (int ti = 0; ti < 2; ti++) {
        const int qt = qts[ti], q0 = qt * 64;
        __syncthreads();   // prev tile's endgame reads done before zeroing

        // zero merge buffers
        {
            f4v z = {};
            float* ob = &Obuf[sr * 68 + sc];
            *(f4v*)&ob[0] = z; *(f4v*)&ob[4] = z;
            *(f4v*)&ob[8] = z; *(f4v*)&ob[12] = z;
            if (tid < 64) lbuf[tid] = 0.0f;
        }

        // Q B-frags (all 64 q rows of this tile), loop-invariant, from global
        s8v qf[4][2];
        #pragma unroll
        for (int qb = 0; qb < 4; qb++) {
            const ushort_t* qrow = qkv
                + ((size_t)(b * LSEQ + q0 + qb * 16 + ln)) * (3 * DH) + h * HDIM;
            qf[qb][0] = *(const s8v*)(qrow + quad * 8);
            qf[qb][1] = *(const s8v*)(qrow + 32 + quad * 8);
        }

        f4v o[4][4] = {};      // [qb][db] : O[q=qb*16+quad*4+reg][d=db*16+ln]
        float lp[4] = {};      // per-lane l partials per qb

        size_t gk = ((size_t)(b * LSEQ + sr)) * (3 * DH) + DH + h * HDIM + sc;
        size_t gv = ((size_t)((b * NH + h) * 64 + sr)) * LSEQ + sc;
        uint4 pk0 = *(const uint4*)&qkv[gk];
        uint4 pk1 = *(const uint4*)&qkv[gk + 8];
        uint4 pv0 = *(const uint4*)&vt[gv];
        uint4 pv1 = *(const uint4*)&vt[gv + 8];

        for (int kt = 0; kt <= qt; kt++) {
            __syncthreads();
            *(uint4*)&Ks[ldsw]     = pk0;
            *(uint4*)&Ks[ldsw + 8] = pk1;
            *(uint4*)&Vs[ldsw]     = pv0;
            *(uint4*)&Vs[ldsw + 8] = pv1;
            if (kt < qt) {
                gk += kstep; gv += 64;
                pk0 = *(const uint4*)&qkv[gk];
                pk1 = *(const uint4*)&qkv[gk + 8];
                pv0 = *(const uint4*)&vt[gv];
                pv1 = *(const uint4*)&vt[gv + 8];
            }
            __syncthreads();

            // this wave's k-quarter fragments
            s8v ka0 = *(const s8v*)&Ks[(w * 16 + ln) * 72 + quad * 8];
            s8v ka1 = *(const s8v*)&Ks[(w * 16 + ln) * 72 + 32 + quad * 8];
            s4v vf[4];
            #pragma unroll
            for (int db = 0; db < 4; db++)
                vf[db] = *(const s4v*)&Vs[(db * 16 + ln) * 72 + w * 16 + quad * 4];

            #pragma unroll
            for (int qb = 0; qb < 4; qb++) {
                // S^T[k = kt*64 + w*16 + quad*4 + reg][q = q0 + qb*16 + ln]
                f4v s = {};
                s = __builtin_amdgcn_mfma_f32_16x16x32_bf16(ka0, qf[qb][0], s, 0, 0, 0);
                s = __builtin_amdgcn_mfma_f32_16x16x32_bf16(ka1, qf[qb][1], s, 0, 0, 0);

                float pv[4];
                if (kt == qt) {
                    const int q = q0 + qb * 16 + ln;
                    #pragma unroll
                    for (int reg = 0; reg < 4; reg++) {
                        int kidx = kt * 64 + w * 16 + quad * 4 + reg;
                        bool valid = (kidx <= q) && (kidx >= 1 || q == 0);
                        pv[reg] = valid ? __builtin_amdgcn_exp2f(s[reg] * C_EXP) : 0.0f;
                    }
                } else {
                    #pragma unroll
                    for (int reg = 0; reg < 4; reg++)
                        pv[reg] = __builtin_amdgcn_exp2f(s[reg] * C_EXP);
                    if (kt == 0 && w == 0 && quad == 0)   // kidx==0, qt>0 here
                        pv[0] = 0.0f;
                }

                lp[qb] += (pv[0] + pv[1]) + (pv[2] + pv[3]);

                s4v pf = { (short)f2bf(pv[0]), (short)f2bf(pv[1]),
                           (short)f2bf(pv[2]), (short)f2bf(pv[3]) };
                #pragma unroll
                for (int db = 0; db < 4; db++)
                    o[qb][db] = __builtin_amdgcn_mfma_f32_16x16x16bf16_1k(
                        pf, vf[db], o[qb][db], 0, 0, 0);
            }
        }

        // merge partials across waves (k-quarters)
        #pragma unroll
        for (int qb = 0; qb < 4; qb++)
            atomicAdd(&lbuf[qb * 16 + ln], lp[qb]);
        #pragma unroll
        for (int qb = 0; qb < 4; qb++)
            #pragma unroll
            for (int db = 0; db < 4; db++)
                #pragma unroll
                for (int reg = 0; reg < 4; reg++)
                    atomicAdd(&Obuf[(qb * 16 + quad * 4 + reg) * 68 + db * 16 + ln],
                              o[qb][db][reg]);
        __syncthreads();

        // normalize + write att (bf16): thread -> (q = sr, d-chunk = sc)
        {
            float linv = 1.0f / lbuf[sr];
            const float* ob = &Obuf[sr * 68 + sc];
            ushort_t tmp[16];
            #pragma unroll
            for (int j = 0; j < 16; j++) tmp[j] = f2bf(ob[j] * linv);
            size_t g = ((size_t)(b * LSEQ + q0 + sr)) * DH + h * HDIM + sc;
            *(uint4*)&att[g]     = *(uint4*)&tmp[0];
            *(uint4*)&att[g + 8] = *(uint4*)&tmp[8];
        }
    }
}

// ---------------------------------------------------------------------------
extern "C" void kernel_launch(void* const* d_in, const int* in_sizes, int n_in,
                              void* d_out, int out_size, void* d_ws, size_t ws_size,
                              hipStream_t stream)
{
    const float* x     = (const float*)d_in[0];  // [2,4096,512]
    const float* w_in  = (const float*)d_in[1];  // [512,1536]
    const float* b_in  = (const float*)d_in[2];  // [1536]
    const float* w_out = (const float*)d_in[3];  // [512,512]
    const float* b_out = (const float*)d_in[4];  // [512]
    float* out = (float*)d_out;                  // [2,4096,512] fp32

    const int M = BSZ * LSEQ;                    // 8192
    char* ws = (char*)d_ws;
    ushort_t* xb    = (ushort_t*)ws;                       ws += (size_t)M * DH * 2;
    ushort_t* w_inT = (ushort_t*)ws;                       ws += (size_t)3 * DH * DH * 2;
    ushort_t* w_outT= (ushort_t*)ws;                       ws += (size_t)DH * DH * 2;
    ushort_t* qkvb  = (ushort_t*)ws;                       ws += (size_t)M * 3 * DH * 2;
    ushort_t* vtb   = (ushort_t*)ws;                       ws += (size_t)M * DH * 2;
    ushort_t* attb  = (ushort_t*)ws;

    cast_bf16<<<(M * DH / 4 + 255) / 256, 256, 0, stream>>>(x, xb, M * DH);
    transpose_cast<<<dim3(3 * DH / 32, DH / 32), 256, 0, stream>>>(w_in, w_inT, DH, 3 * DH);
    transpose_cast<<<dim3(DH / 32, DH / 32), 256, 0, stream>>>(w_out, w_outT, DH, DH);

    gemm_bt<ushort_t><<<dim3(3 * DH / 128, M / 128), 256, 0, stream>>>(
        xb, w_inT, b_in, qkvb, M, 3 * DH, DH);

    vtrans<<<dim3(LSEQ / 64, NH, BSZ), 256, 0, stream>>>(qkvb, vtb);

    flash_mfma<<<dim3(32, NH, BSZ), 256, 0, stream>>>(qkvb, vtb, attb);

    gemm_bt<float><<<dim3(DH / 128, M / 128), 256, 0, stream>>>(
        attb, w_outT, b_out, out, M, DH, DH);
}

// Round 8
// 209.445 us; speedup vs baseline: 1.2936x; 1.2936x over previous
//
#include <hip/hip_runtime.h>
#include <hip/hip_bf16.h>

#define BSZ   2
#define LSEQ  4096
#define DH    512
#define NH    8
#define HDIM  64

typedef unsigned short ushort_t;
typedef __attribute__((ext_vector_type(8))) short s8v;    // 8 bf16 = 4 VGPRs
typedef __attribute__((ext_vector_type(4))) float f4v;    // MFMA accumulator

__device__ __forceinline__ ushort_t f2bf(float f) {
    __hip_bfloat16 h = __float2bfloat16(f);
    return *(ushort_t*)&h;
}

// async global->LDS, 16B per lane; LDS dest = wave-uniform base + lane*16B
__device__ __forceinline__ void gld_lds16(const ushort_t* g, ushort_t* l) {
    __builtin_amdgcn_global_load_lds(
        (const __attribute__((address_space(1))) void*)g,
        (__attribute__((address_space(3))) void*)l, 16, 0, 0);
}

// ---------------------------------------------------------------------------
__global__ __launch_bounds__(256) void cast_bf16(const float* __restrict__ src,
                                                 ushort_t* __restrict__ dst, int n)
{
    int i = (blockIdx.x * 256 + threadIdx.x) * 4;
    if (i + 3 < n) {
        float4 v = *(const float4*)&src[i];
        ushort_t o[4] = {f2bf(v.x), f2bf(v.y), f2bf(v.z), f2bf(v.w)};
        *(uint2*)&dst[i] = *(uint2*)o;
    }
}

// ---------------------------------------------------------------------------
__global__ __launch_bounds__(256) void transpose_cast(const float* __restrict__ src,
                                                      ushort_t* __restrict__ dst,
                                                      int R, int C)
{
    __shared__ float tile[32][33];
    int r0 = blockIdx.y * 32, c0 = blockIdx.x * 32;
    int t = threadIdx.x;
    int tr = t >> 5, tc = t & 31;
    #pragma unroll
    for (int i = 0; i < 4; i++)
        tile[tr + 8 * i][tc] = src[(size_t)(r0 + tr + 8 * i) * C + c0 + tc];
    __syncthreads();
    #pragma unroll
    for (int i = 0; i < 4; i++) {
        int oc = tr + 8 * i;
        dst[(size_t)(c0 + oc) * R + r0 + tc] = f2bf(tile[tc][oc]);
    }
}

// ---------------------------------------------------------------------------
__global__ __launch_bounds__(256) void vtrans(const ushort_t* __restrict__ qkv,
                                              ushort_t* __restrict__ vt)
{
    __shared__ ushort_t T[64][72];
    const int lt = blockIdx.x, h = blockIdx.y, b = blockIdx.z;
    const int l0 = lt * 64;
    const int t = threadIdx.x;
    {
        int r = t >> 2, c = (t & 3) * 16;
        size_t g = ((size_t)(b * LSEQ + l0 + r)) * (3 * DH) + 2 * DH + h * HDIM + c;
        *(uint4*)&T[r][c]     = *(const uint4*)&qkv[g];
        *(uint4*)&T[r][c + 8] = *(const uint4*)&qkv[g + 8];
    }
    __syncthreads();
    {
        int d = t >> 2, cl = (t & 3) * 16;
        ushort_t tmp[16];
        #pragma unroll
        for (int j = 0; j < 16; j++) tmp[j] = T[cl + j][d];
        size_t g = ((size_t)((b * NH + h) * 64 + d)) * LSEQ + l0 + cl;
        *(uint4*)&vt[g]     = *(uint4*)&tmp[0];
        *(uint4*)&vt[g + 8] = *(uint4*)&tmp[8];
    }
}

// ---------------------------------------------------------------------------
// bf16 MFMA GEMM (m97 structure), unchanged.
// ---------------------------------------------------------------------------
template <typename OUT>
__global__ __launch_bounds__(256) void gemm_bt(const ushort_t* __restrict__ A,
                                               const ushort_t* __restrict__ Bt,
                                               const float* __restrict__ bias,
                                               OUT* __restrict__ C,
                                               int M, int N, int K)
{
    __shared__ ushort_t As[128 * 32];
    __shared__ ushort_t Bs[128 * 32];
    const int tid = threadIdx.x;
    const int row0 = blockIdx.y * 128, col0 = blockIdx.x * 128;
    const int wid = tid >> 6, lane = tid & 63;
    const int wm = wid >> 1, wn = wid & 1;
    const int quad = lane >> 4, ln = lane & 15;

    f4v acc[4][4] = {};

    const int srow = (lane >> 2);
    const int scol = (lane & 3) * 8;

    for (int k0 = 0; k0 < K; k0 += 32) {
        #pragma unroll
        for (int t = 0; t < 2; t++) {
            int chunk = wid * 2 + t;
            int r = chunk * 16 + srow;
            gld_lds16(&A[(size_t)(row0 + r) * K + k0 + scol], &As[chunk * 512]);
            gld_lds16(&Bt[(size_t)(col0 + r) * K + k0 + scol], &Bs[chunk * 512]);
        }
        __syncthreads();
        s8v af[4], bf[4];
        #pragma unroll
        for (int mt = 0; mt < 4; mt++)
            af[mt] = *(const s8v*)&As[(wm * 64 + mt * 16 + ln) * 32 + quad * 8];
        #pragma unroll
        for (int nt = 0; nt < 4; nt++)
            bf[nt] = *(const s8v*)&Bs[(wn * 64 + nt * 16 + ln) * 32 + quad * 8];
        #pragma unroll
        for (int mt = 0; mt < 4; mt++)
            #pragma unroll
            for (int nt = 0; nt < 4; nt++)
                acc[mt][nt] = __builtin_amdgcn_mfma_f32_16x16x32_bf16(
                    af[mt], bf[nt], acc[mt][nt], 0, 0, 0);
        __syncthreads();
    }

    #pragma unroll
    for (int mt = 0; mt < 4; mt++) {
        #pragma unroll
        for (int nt = 0; nt < 4; nt++) {
            int c = col0 + wn * 64 + nt * 16 + ln;
            float bv = bias[c];
            #pragma unroll
            for (int reg = 0; reg < 4; reg++) {
                int r = row0 + wm * 64 + mt * 16 + quad * 4 + reg;
                float v = acc[mt][nt][reg] + bv;
                if constexpr (sizeof(OUT) == 2)
                    C[(size_t)r * N + c] = (OUT)f2bf(v);
                else
                    C[(size_t)r * N + c] = v;
            }
        }
    }
}

// ---------------------------------------------------------------------------
// Flash v5: v3 per-iter structure (S^T QK, register P spill to wave-private
// Ps rows, fixed-max softmax), but UNIFORM schedule: block = (pair p, q-half).
// grid.x=64: p = x>>1 handles qts {63-p, p} sequentially; qh = x&1 selects
// 32 q-rows. 128 threads = 2 waves x 16 q-rows. Every block = exactly 65
// iters -> no triangular tail; 1024 blocks (~4/CU) for cross-block overlap.
// ---------------------------------------------------------------------------
__global__ __launch_bounds__(128) void flash_mfma(const ushort_t* __restrict__ qkv,
                                                  const ushort_t* __restrict__ vt,
                                                  ushort_t* __restrict__ att)
{
    __shared__ ushort_t Ks[64 * 72];   // [kseq][d]
    __shared__ ushort_t Vs[64 * 72];   // [d][kseq]
    __shared__ ushort_t Ps[32 * 72];   // [q(32)][kseq]

    const int p  = blockIdx.x >> 1;    // 0..31
    const int qh = blockIdx.x & 1;     // q-half within tile
    const int h = blockIdx.y, b = blockIdx.z;
    const int tid = threadIdx.x;
    const int w = tid >> 6, lane = tid & 63;   // w in {0,1}
    const int quad = lane >> 4, ln = lane & 15;

    // staging map: 128 threads cover 64 rows x 64 cols (2 threads/row)
    const int sr = tid >> 1, sc = (tid & 1) * 32;
    const int ldsw = sr * 72 + sc;
    const size_t kstep = (size_t)64 * 3 * DH;
    const float C_EXP = 0.18033688011112042f;  // 0.125 * log2(e)

    const int qts[2] = {63 - p, p};

    for (int ti = 0; ti < 2; ti++) {
        const int qt = qts[ti], q0 = qt * 64;
        // this wave's q-row group (16 rows)
        const int qrow0 = q0 + qh * 32 + w * 16;

        // Q B-frags, loop-invariant, direct from global
        const ushort_t* qrow = qkv + ((size_t)(b * LSEQ + qrow0 + ln)) * (3 * DH) + h * HDIM;
        s8v qa0 = *(const s8v*)(qrow + quad * 8);
        s8v qa1 = *(const s8v*)(qrow + 32 + quad * 8);

        float l_s = 0.0f;
        f4v o_acc[4] = {};

        size_t gk = ((size_t)(b * LSEQ + sr)) * (3 * DH) + DH + h * HDIM + sc;
        size_t gv = ((size_t)((b * NH + h) * 64 + sr)) * LSEQ + sc;
        uint4 pk0 = *(const uint4*)&qkv[gk];
        uint4 pk1 = *(const uint4*)&qkv[gk + 8];
        uint4 pk2 = *(const uint4*)&qkv[gk + 16];
        uint4 pk3 = *(const uint4*)&qkv[gk + 24];
        uint4 pv0 = *(const uint4*)&vt[gv];
        uint4 pv1 = *(const uint4*)&vt[gv + 8];
        uint4 pv2 = *(const uint4*)&vt[gv + 16];
        uint4 pv3 = *(const uint4*)&vt[gv + 24];

        const int prow = (w * 16 + ln) * 72;   // this lane's q-row in Ps

        for (int kt = 0; kt <= qt; kt++) {
            const int k0 = kt * 64;
            __syncthreads();   // all waves done reading prev Ks/Vs
            *(uint4*)&Ks[ldsw]      = pk0;
            *(uint4*)&Ks[ldsw + 8]  = pk1;
            *(uint4*)&Ks[ldsw + 16] = pk2;
            *(uint4*)&Ks[ldsw + 24] = pk3;
            *(uint4*)&Vs[ldsw]      = pv0;
            *(uint4*)&Vs[ldsw + 8]  = pv1;
            *(uint4*)&Vs[ldsw + 16] = pv2;
            *(uint4*)&Vs[ldsw + 24] = pv3;
            if (kt < qt) {
                gk += kstep; gv += 64;
                pk0 = *(const uint4*)&qkv[gk];
                pk1 = *(const uint4*)&qkv[gk + 8];
                pk2 = *(const uint4*)&qkv[gk + 16];
                pk3 = *(const uint4*)&qkv[gk + 24];
                pv0 = *(const uint4*)&vt[gv];
                pv1 = *(const uint4*)&vt[gv + 8];
                pv2 = *(const uint4*)&vt[gv + 16];
                pv3 = *(const uint4*)&vt[gv + 24];
            }
            __syncthreads();

            // S^T = K @ Q^T : s[nt][reg] = S^T[k0+nt*16+quad*4+reg][qrow0+ln]
            f4v s[4] = {};
            #pragma unroll
            for (int nt = 0; nt < 4; nt++) {
                s8v kb0 = *(const s8v*)&Ks[(nt * 16 + ln) * 72 + quad * 8];
                s8v kb1 = *(const s8v*)&Ks[(nt * 16 + ln) * 72 + 32 + quad * 8];
                s[nt] = __builtin_amdgcn_mfma_f32_16x16x32_bf16(kb0, qa0, s[nt], 0, 0, 0);
                s[nt] = __builtin_amdgcn_mfma_f32_16x16x32_bf16(kb1, qa1, s[nt], 0, 0, 0);
            }

            // p = exp(s/8); mask only on diagonal / first tile
            float pp[4][4];   // [nt][reg], k = k0 + nt*16 + quad*4 + reg
            const int q = qrow0 + ln;
            if (kt == qt) {
                #pragma unroll
                for (int nt = 0; nt < 4; nt++) {
                    #pragma unroll
                    for (int reg = 0; reg < 4; reg++) {
                        int kidx = k0 + nt * 16 + quad * 4 + reg;
                        bool valid = (kidx <= q) && (kidx >= 1 || q == 0);
                        pp[nt][reg] = valid ? __builtin_amdgcn_exp2f(s[nt][reg] * C_EXP) : 0.0f;
                    }
                }
            } else {
                #pragma unroll
                for (int nt = 0; nt < 4; nt++)
                    #pragma unroll
                    for (int reg = 0; reg < 4; reg++)
                        pp[nt][reg] = __builtin_amdgcn_exp2f(s[nt][reg] * C_EXP);
                if (kt == 0 && quad == 0)   // k==0 column invalid (q >= 64 here)
                    pp[0][0] = 0.0f;
            }

            #pragma unroll
            for (int nt = 0; nt < 4; nt++)
                l_s += (pp[nt][0] + pp[nt][1]) + (pp[nt][2] + pp[nt][3]);

            // packed spill: 4 contiguous k's per nt -> one b64 write each
            #pragma unroll
            for (int nt = 0; nt < 4; nt++) {
                unsigned int lo = (unsigned int)f2bf(pp[nt][0]) | ((unsigned int)f2bf(pp[nt][1]) << 16);
                unsigned int hi = (unsigned int)f2bf(pp[nt][2]) | ((unsigned int)f2bf(pp[nt][3]) << 16);
                uint2 pkd; pkd.x = lo; pkd.y = hi;
                *(uint2*)&Ps[prow + nt * 16 + quad * 4] = pkd;
            }
            // wave-private rows: no barrier needed

            // O += P @ V
            s8v pa0 = *(const s8v*)&Ps[prow + quad * 8];
            s8v pa1 = *(const s8v*)&Ps[prow + 32 + quad * 8];
            #pragma unroll
            for (int dt = 0; dt < 4; dt++) {
                s8v vb0 = *(const s8v*)&Vs[(dt * 16 + ln) * 72 + quad * 8];
                s8v vb1 = *(const s8v*)&Vs[(dt * 16 + ln) * 72 + 32 + quad * 8];
                o_acc[dt] = __builtin_amdgcn_mfma_f32_16x16x32_bf16(pa0, vb0, o_acc[dt], 0, 0, 0);
                o_acc[dt] = __builtin_amdgcn_mfma_f32_16x16x32_bf16(pa1, vb1, o_acc[dt], 0, 0, 0);
            }
        }

        // reduce l over 4 quads, broadcast, normalize, write
        float lf = l_s;
        lf += __shfl_xor(lf, 16);
        lf += __shfl_xor(lf, 32);          // every lane: l_total[q = ln]
        #pragma unroll
        for (int reg = 0; reg < 4; reg++) {
            float linv = 1.0f / __shfl(lf, quad * 4 + reg);
            size_t r = (size_t)(b * LSEQ + qrow0 + quad * 4 + reg);
            #pragma unroll
            for (int dt = 0; dt < 4; dt++)
                att[r * DH + h * HDIM + dt * 16 + ln] = f2bf(o_acc[dt][reg] * linv);
        }
    }
}

// ---------------------------------------------------------------------------
extern "C" void kernel_launch(void* const* d_in, const int* in_sizes, int n_in,
                              void* d_out, int out_size, void* d_ws, size_t ws_size,
                              hipStream_t stream)
{
    const float* x     = (const float*)d_in[0];  // [2,4096,512]
    const float* w_in  = (const float*)d_in[1];  // [512,1536]
    const float* b_in  = (const float*)d_in[2];  // [1536]
    const float* w_out = (const float*)d_in[3];  // [512,512]
    const float* b_out = (const float*)d_in[4];  // [512]
    float* out = (float*)d_out;                  // [2,4096,512] fp32

    const int M = BSZ * LSEQ;                    // 8192
    char* ws = (char*)d_ws;
    ushort_t* xb    = (ushort_t*)ws;                       ws += (size_t)M * DH * 2;
    ushort_t* w_inT = (ushort_t*)ws;                       ws += (size_t)3 * DH * DH * 2;
    ushort_t* w_outT= (ushort_t*)ws;                       ws += (size_t)DH * DH * 2;
    ushort_t* qkvb  = (ushort_t*)ws;                       ws += (size_t)M * 3 * DH * 2;
    ushort_t* vtb   = (ushort_t*)ws;                       ws += (size_t)M * DH * 2;
    ushort_t* attb  = (ushort_t*)ws;

    cast_bf16<<<(M * DH / 4 + 255) / 256, 256, 0, stream>>>(x, xb, M * DH);
    transpose_cast<<<dim3(3 * DH / 32, DH / 32), 256, 0, stream>>>(w_in, w_inT, DH, 3 * DH);
    transpose_cast<<<dim3(DH / 32, DH / 32), 256, 0, stream>>>(w_out, w_outT, DH, DH);

    gemm_bt<ushort_t><<<dim3(3 * DH / 128, M / 128), 256, 0, stream>>>(
        xb, w_inT, b_in, qkvb, M, 3 * DH, DH);

    vtrans<<<dim3(LSEQ / 64, NH, BSZ), 256, 0, stream>>>(qkvb, vtb);

    flash_mfma<<<dim3(64, NH, BSZ), 128, 0, stream>>>(qkvb, vtb, attb);

    gemm_bt<float><<<dim3(DH / 128, M / 128), 256, 0, stream>>>(
        attb, w_outT, b_out, out, M, DH, DH);
}